// Round 1
// baseline (1560.476 us; speedup 1.0000x reference)
//
#include <hip/hip_runtime.h>
#include <hip/hip_bf16.h>
#include <math.h>

// Problem constants (fixed shapes from setup_inputs)
#define NB 8
#define CI 256
#define CD 128
#define HH 128
#define WW 128
#define HW (HH*WW)          // 16384
#define AANG 180
#define RRHO 180
#define PADD 182            // 180 + 2 (zero pad for 3x3 convs)
#define M2 (AANG*RRHO)      // 32400 output pixels per image for conv2/3

typedef __attribute__((ext_vector_type(8))) short short8;
typedef __attribute__((ext_vector_type(4))) float floatx4;

static __device__ __forceinline__ void async_cp16(const void* g, void* l) {
  __builtin_amdgcn_global_load_lds((const __attribute__((address_space(1))) unsigned int*)g,
                                   (__attribute__((address_space(3))) unsigned int*)l,
                                   16, 0, 0);
}

static __device__ __forceinline__ unsigned short f2bf(float f) {
  unsigned int u = __builtin_bit_cast(unsigned int, f);
  unsigned int r = (u + 0x7fffu + ((u >> 16) & 1u)) >> 16;
  return (unsigned short)r;
}

// ---------------------------------------------------------------------------
// prep: weight bf16 repack (k-contiguous per co) + BN scale/shift folding
// wK2/wK3 layout: [co][k], k = (dy*3+dx)*128 + ci
// ---------------------------------------------------------------------------
__global__ void prep_kernel(const float* __restrict__ w1, const float* __restrict__ w2,
                            const float* __restrict__ w3,
                            const float* b1, const float* g1, const float* be1,
                            const float* m1, const float* v1,
                            const float* b2, const float* g2, const float* be2,
                            const float* m2, const float* v2,
                            const float* b3, const float* g3, const float* be3,
                            const float* m3, const float* v3,
                            unsigned short* __restrict__ wK1, unsigned short* __restrict__ wK2,
                            unsigned short* __restrict__ wK3,
                            float* __restrict__ sc, float* __restrict__ sh) {
  int idx = blockIdx.x * 256 + threadIdx.x;
  if (idx < 32768) {
    wK1[idx] = f2bf(w1[idx]);                      // w1 is already [co][ci]
  } else if (idx < 32768 + 147456) {
    int i = idx - 32768;
    int co = i / 1152, k = i % 1152;
    int dydx = k >> 7, ci = k & 127;
    wK2[(size_t)co*1152 + k] = f2bf(w2[(size_t)(co*128 + ci)*9 + dydx]);
  } else if (idx < 32768 + 2*147456) {
    int i = idx - 32768 - 147456;
    int co = i / 1152, k = i % 1152;
    int dydx = k >> 7, ci = k & 127;
    wK3[(size_t)co*1152 + k] = f2bf(w3[(size_t)(co*128 + ci)*9 + dydx]);
  } else if (idx < 32768 + 2*147456 + 384) {
    int j = idx - 32768 - 2*147456;
    int c = j >> 7, co = j & 127;
    const float* b  = c==0?b1 :(c==1?b2 :b3);
    const float* g  = c==0?g1 :(c==1?g2 :g3);
    const float* be = c==0?be1:(c==1?be2:be3);
    const float* m  = c==0?m1 :(c==1?m2 :m3);
    const float* v  = c==0?v1 :(c==1?v2 :v3);
    float s = g[co] * rsqrtf(v[co] + 1e-5f);
    sc[c*128 + co] = s;
    sh[c*128 + co] = (b[co] - m[co]) * s + be[co];
  }
}

// ---------------------------------------------------------------------------
// Hough binning tables. fp64 to exactly match numpy (round-half-even via rint).
// irho = int(sqrt(128^2+128^2)+1)/(180-1) = 182/179
// ---------------------------------------------------------------------------
__global__ void hist_kernel(unsigned char* __restrict__ seg, unsigned int* __restrict__ offs) {
  int a = blockIdx.x, t = threadIdx.x;
  __shared__ unsigned int h[RRHO];
  if (t < RRHO) h[t] = 0;
  __syncthreads();
  double th = (double)a * (M_PI / 180.0);
  double Cc = cos(th) / (182.0 / 179.0);
  double Ss = sin(th) / (182.0 / 179.0);
  for (int p = t; p < HW; p += 256) {
    int x = (p & 127) - 64;   // width index
    int y = (p >> 7) - 64;    // height index
    int r = (int)rint(Cc * (double)x + Ss * (double)y) + 90;
    r = r < 0 ? 0 : (r > 179 ? 179 : r);
    seg[(size_t)a*HW + p] = (unsigned char)r;
    atomicAdd(&h[r], 1u);
  }
  __syncthreads();
  if (t == 0) {
    unsigned int run = 0;
    for (int r = 0; r < RRHO; ++r) { offs[a*192 + r] = run; run += h[r]; }
    offs[a*192 + RRHO] = run;
  }
}

__global__ void fill_kernel(const unsigned char* __restrict__ seg,
                            const unsigned int* __restrict__ offs,
                            unsigned int* __restrict__ lst) {
  int a = blockIdx.x, t = threadIdx.x;
  __shared__ unsigned int pos[RRHO];
  if (t < RRHO) pos[t] = offs[a*192 + t];
  __syncthreads();
  for (int p = t; p < HW; p += 256) {
    int r = seg[(size_t)a*HW + p];
    unsigned int ix = atomicAdd(&pos[r], 1u);
    lst[(size_t)a*HW + ix] = (unsigned int)p;
  }
}

// Zero the 1-px borders of the two padded activation buffers (ws is poisoned).
__global__ void zero_border(uint4* __restrict__ accP, uint4* __restrict__ y2P) {
  int idx = blockIdx.x * 256 + threadIdx.x;
  if (idx >= NB * PADD * PADD) return;
  int rc = idx % (PADD * PADD);
  int row = rc / PADD, col = rc % PADD;
  if (row != 0 && row != PADD-1 && col != 0 && col != PADD-1) return;
  uint4 z = {0u, 0u, 0u, 0u};
  size_t base = (size_t)idx * 16;  // 128 bf16 = 16 uint4 per cell
  #pragma unroll
  for (int i = 0; i < 16; ++i) { accP[base + i] = z; y2P[base + i] = z; }
}

// ---------------------------------------------------------------------------
// conv1: 1x1 conv as MFMA GEMM. A = x (fp32, transposed+converted in staging),
// B = wK1 bf16 (global_load_lds). Output f[n][pixel][co] bf16 channels-last.
// ---------------------------------------------------------------------------
__global__ __launch_bounds__(256) void conv1_kernel(
    const float* __restrict__ x, const unsigned short* __restrict__ wK,
    const float* __restrict__ sc, const float* __restrict__ sh,
    unsigned short* __restrict__ f) {
  __shared__ short Al[4*128*8];
  __shared__ short Bl[4*128*8];
  int t = threadIdx.x;
  int m0 = blockIdx.x * 128;
  int n = blockIdx.y;
  int lane = t & 63, wv = t >> 6, wm = wv & 1, wn = wv >> 1;
  int mloc = t & 127, octb = t >> 7;
  floatx4 acc[4][4];
  #pragma unroll
  for (int i = 0; i < 4; ++i)
    #pragma unroll
    for (int j = 0; j < 4; ++j) acc[i][j] = (floatx4){0.f, 0.f, 0.f, 0.f};
  const float* xn = x + (size_t)n * CI * HW;
  for (int kc = 0; kc < 8; ++kc) {
    if (kc) __syncthreads();
    // A: load 8 k-strided fp32 per pass, convert, transpose into [oct][m][8]
    #pragma unroll
    for (int j = 0; j < 2; ++j) {
      int oct = octb + 2*j;
      const float* src = xn + (size_t)(kc*32 + oct*8) * HW + m0 + mloc;
      float v[8];
      #pragma unroll
      for (int e = 0; e < 8; ++e) v[e] = src[(size_t)e * HW];
      short8 pk;
      #pragma unroll
      for (int e = 0; e < 8; ++e) pk[e] = (short)f2bf(v[e]);
      *reinterpret_cast<short8*>(&Al[(size_t)(t + 256*j) * 8]) = pk;
    }
    // B: async 16B direct-to-LDS
    #pragma unroll
    for (int j = 0; j < 2; ++j) {
      int oct = octb + 2*j;
      async_cp16(wK + (size_t)mloc * 256 + kc*32 + oct*8,
                 &Bl[(size_t)((t & 0xFFC0) + 256*j) * 8]);
    }
    __syncthreads();
    int q = lane >> 4, l15 = lane & 15;
    short8 af[4], bfr[4];
    #pragma unroll
    for (int i = 0; i < 4; ++i)
      af[i] = *reinterpret_cast<const short8*>(&Al[((q*128) + wm*64 + i*16 + l15) * 8]);
    #pragma unroll
    for (int j = 0; j < 4; ++j)
      bfr[j] = *reinterpret_cast<const short8*>(&Bl[((q*128) + wn*64 + j*16 + l15) * 8]);
    #pragma unroll
    for (int i = 0; i < 4; ++i)
      #pragma unroll
      for (int j = 0; j < 4; ++j)
        acc[i][j] = __builtin_amdgcn_mfma_f32_16x16x32_bf16(af[i], bfr[j], acc[i][j], 0, 0, 0);
  }
  int q = lane >> 4, l15 = lane & 15;
  #pragma unroll
  for (int j = 0; j < 4; ++j) {
    int co = wn*64 + j*16 + l15;
    float s = sc[co], hb = sh[co];
    #pragma unroll
    for (int i = 0; i < 4; ++i) {
      #pragma unroll
      for (int rg = 0; rg < 4; ++rg) {
        int m = m0 + wm*64 + i*16 + q*4 + rg;
        float v = acc[i][j][rg] * s + hb;
        v = fmaxf(v, 0.f);
        f[((size_t)n * HW + m) * 128 + co] = f2bf(v);
      }
    }
  }
}

// ---------------------------------------------------------------------------
// DHT gather: block = (n, angle); wave w owns rho bins [w*45, w*45+45);
// lane = channel pair. Register accumulation; reads bf16x2 channel words.
// Writes padded accP[n][a+1][r+1][c] bf16.
// ---------------------------------------------------------------------------
__global__ __launch_bounds__(256) void dht_kernel(
    const unsigned int* __restrict__ lst, const unsigned int* __restrict__ offs,
    const unsigned int* __restrict__ f, unsigned int* __restrict__ accP) {
  int b = blockIdx.x;
  int n = b & 7;               // XCD round-robin -> one image per XCD L2
  int a = b >> 3;
  int t = threadIdx.x;
  int w = __builtin_amdgcn_readfirstlane(t >> 6);
  int lane = t & 63;
  const unsigned int* fn = f + (size_t)n * HW * 64;
  const unsigned int* La = lst + (size_t)a * HW;
  for (int ri = 0; ri < 45; ++ri) {
    int r = w * 45 + ri;
    unsigned int o0 = offs[a*192 + r];
    unsigned int o1 = offs[a*192 + r + 1];
    int cnt = (int)(o1 - o0);
    const unsigned int* L = La + o0;
    float s0a = 0.f, s1a = 0.f, s0b = 0.f, s1b = 0.f;
    int i = 0;
    for (; i + 2 <= cnt; i += 2) {
      unsigned int p0 = L[i], p1 = L[i+1];
      unsigned int v0 = fn[(size_t)p0*64 + lane];
      unsigned int v1 = fn[(size_t)p1*64 + lane];
      s0a += __builtin_bit_cast(float, v0 << 16);
      s1a += __builtin_bit_cast(float, v0 & 0xffff0000u);
      s0b += __builtin_bit_cast(float, v1 << 16);
      s1b += __builtin_bit_cast(float, v1 & 0xffff0000u);
    }
    if (i < cnt) {
      unsigned int p0 = L[i];
      unsigned int v0 = fn[(size_t)p0*64 + lane];
      s0a += __builtin_bit_cast(float, v0 << 16);
      s1a += __builtin_bit_cast(float, v0 & 0xffff0000u);
    }
    float s0 = s0a + s0b, s1 = s1a + s1b;
    unsigned int packed = (unsigned int)f2bf(s0) | ((unsigned int)f2bf(s1) << 16);
    size_t o = (((size_t)n*PADD + (a+1))*PADD + (r+1))*64 + lane;
    __builtin_nontemporal_store(packed, &accP[o]);
  }
}

// ---------------------------------------------------------------------------
// 3x3 conv as implicit GEMM over padded channels-last input.
// MODE 1: conv2 -> bf16 padded channels-last out. rows = spatial, cols = co.
// MODE 2: conv3 -> fp32 NCHW d_out. Operands swapped: rows = co, cols = spatial
//         so stores are contiguous along rho.
// ---------------------------------------------------------------------------
template<int MODE>
__global__ __launch_bounds__(256) void conv3x3_kernel(
    const unsigned short* __restrict__ inP,   // [N][182][182][128] bf16
    const unsigned short* __restrict__ wK,    // [128][1152] bf16
    const float* __restrict__ sc, const float* __restrict__ sh,
    void* __restrict__ outp) {
  __shared__ short Al[4*128*8];
  __shared__ short Bl[4*128*8];
  int t = threadIdx.x;
  int m0 = blockIdx.x * 128;
  int n = blockIdx.y;
  int lane = t & 63, wv = t >> 6, wm = wv & 1, wn = wv >> 1;
  int mloc = t & 127, octb = t >> 7;
  floatx4 acc[4][4];
  #pragma unroll
  for (int i = 0; i < 4; ++i)
    #pragma unroll
    for (int j = 0; j < 4; ++j) acc[i][j] = (floatx4){0.f, 0.f, 0.f, 0.f};
  int mg = m0 + mloc; if (mg > M2 - 1) mg = M2 - 1;
  int oa = mg / 180, orr = mg % 180;
  const unsigned short* rowp = inP + (((size_t)n*PADD + oa)*PADD + orr) * 128;
  const unsigned short* wbase = wK + (size_t)mloc * 1152;
  for (int kc = 0; kc < 36; ++kc) {
    int dydx = kc >> 2, cc = kc & 3;
    int dy = dydx / 3, dx = dydx % 3;
    if (kc) __syncthreads();
    #pragma unroll
    for (int j = 0; j < 2; ++j) {
      int oct = octb + 2*j;
      async_cp16(rowp + ((dy*PADD + dx)*128) + cc*32 + oct*8,
                 &Al[(size_t)((t & 0xFFC0) + 256*j) * 8]);
      async_cp16(wbase + dydx*128 + cc*32 + oct*8,
                 &Bl[(size_t)((t & 0xFFC0) + 256*j) * 8]);
    }
    __syncthreads();
    int q = lane >> 4, l15 = lane & 15;
    short8 rf[4], cf[4];
    #pragma unroll
    for (int i = 0; i < 4; ++i) {
      int off = ((q*128) + wm*64 + i*16 + l15) * 8;
      rf[i] = *reinterpret_cast<const short8*>(MODE == 1 ? &Al[off] : &Bl[off]);
    }
    #pragma unroll
    for (int j = 0; j < 4; ++j) {
      int off = ((q*128) + wn*64 + j*16 + l15) * 8;
      cf[j] = *reinterpret_cast<const short8*>(MODE == 1 ? &Bl[off] : &Al[off]);
    }
    #pragma unroll
    for (int i = 0; i < 4; ++i)
      #pragma unroll
      for (int j = 0; j < 4; ++j)
        acc[i][j] = __builtin_amdgcn_mfma_f32_16x16x32_bf16(rf[i], cf[j], acc[i][j], 0, 0, 0);
  }
  int q = lane >> 4, l15 = lane & 15;
  if (MODE == 1) {
    unsigned short* out = (unsigned short*)outp;
    #pragma unroll
    for (int j = 0; j < 4; ++j) {
      int co = wn*64 + j*16 + l15;
      float s = sc[co], hb = sh[co];
      #pragma unroll
      for (int i = 0; i < 4; ++i) {
        #pragma unroll
        for (int rg = 0; rg < 4; ++rg) {
          int m = m0 + wm*64 + i*16 + q*4 + rg;
          if (m < M2) {
            float v = fmaxf(acc[i][j][rg] * s + hb, 0.f);
            int oa2 = m / 180, or2 = m % 180;
            out[(((size_t)n*PADD + oa2 + 1)*PADD + or2 + 1)*128 + co] = f2bf(v);
          }
        }
      }
    }
  } else {
    float* out = (float*)outp;
    #pragma unroll
    for (int i = 0; i < 4; ++i) {
      #pragma unroll
      for (int rg = 0; rg < 4; ++rg) {
        int co = wm*64 + i*16 + q*4 + rg;
        float s = sc[co], hb = sh[co];
        #pragma unroll
        for (int j = 0; j < 4; ++j) {
          int m = m0 + wn*64 + j*16 + l15;
          if (m < M2) {
            float v = fmaxf(acc[i][j][rg] * s + hb, 0.f);
            out[((size_t)n*128 + co)*M2 + m] = v;
          }
        }
      }
    }
  }
}

// ---------------------------------------------------------------------------
extern "C" void kernel_launch(void* const* d_in, const int* in_sizes, int n_in,
                              void* d_out, int out_size, void* d_ws, size_t ws_size,
                              hipStream_t stream) {
  const float* x  = (const float*)d_in[0];
  const float* w1 = (const float*)d_in[1];
  const float* b1 = (const float*)d_in[2];
  const float* g1 = (const float*)d_in[3];
  const float* be1= (const float*)d_in[4];
  const float* m1 = (const float*)d_in[5];
  const float* v1 = (const float*)d_in[6];
  const float* w2 = (const float*)d_in[7];
  const float* b2 = (const float*)d_in[8];
  const float* g2 = (const float*)d_in[9];
  const float* be2= (const float*)d_in[10];
  const float* m2 = (const float*)d_in[11];
  const float* v2 = (const float*)d_in[12];
  const float* w3 = (const float*)d_in[13];
  const float* b3 = (const float*)d_in[14];
  const float* g3 = (const float*)d_in[15];
  const float* be3= (const float*)d_in[16];
  const float* m3 = (const float*)d_in[17];
  const float* v3 = (const float*)d_in[18];

  size_t off = 0;
  char* ws = (char*)d_ws;
  auto alloc = [&](size_t sz) -> void* {
    void* p = ws + off;
    off = (off + sz + 255) & ~(size_t)255;
    return p;
  };
  unsigned short* fbuf = (unsigned short*)alloc((size_t)NB*HW*128*2);        // 33.6 MB
  unsigned short* accP = (unsigned short*)alloc((size_t)NB*PADD*PADD*128*2); // 67.8 MB
  unsigned short* y2P  = (unsigned short*)alloc((size_t)NB*PADD*PADD*128*2); // 67.8 MB
  unsigned short* wK1  = (unsigned short*)alloc(32768*2);
  unsigned short* wK2  = (unsigned short*)alloc(147456*2);
  unsigned short* wK3  = (unsigned short*)alloc(147456*2);
  float* sc = (float*)alloc(384*4);
  float* sh = (float*)alloc(384*4);
  unsigned char* seg  = (unsigned char*)alloc((size_t)AANG*HW);
  unsigned int* offs  = (unsigned int*)alloc((size_t)AANG*192*4);
  unsigned int* lst   = (unsigned int*)alloc((size_t)AANG*HW*4);

  prep_kernel<<<1282, 256, 0, stream>>>(w1, w2, w3,
      b1, g1, be1, m1, v1, b2, g2, be2, m2, v2, b3, g3, be3, m3, v3,
      wK1, wK2, wK3, sc, sh);
  hist_kernel<<<AANG, 256, 0, stream>>>(seg, offs);
  fill_kernel<<<AANG, 256, 0, stream>>>(seg, offs, lst);
  zero_border<<<(NB*PADD*PADD + 255)/256, 256, 0, stream>>>((uint4*)accP, (uint4*)y2P);
  conv1_kernel<<<dim3(HW/128, NB), 256, 0, stream>>>(x, wK1, sc, sh, fbuf);
  dht_kernel<<<NB*AANG, 256, 0, stream>>>(lst, offs, (const unsigned int*)fbuf,
                                          (unsigned int*)accP);
  conv3x3_kernel<1><<<dim3((M2 + 127)/128, NB), 256, 0, stream>>>(
      accP, wK2, sc + 128, sh + 128, y2P);
  conv3x3_kernel<2><<<dim3((M2 + 127)/128, NB), 256, 0, stream>>>(
      y2P, wK3, sc + 256, sh + 256, d_out);
}

// Round 2
// 1107.199 us; speedup vs baseline: 1.4094x; 1.4094x over previous
//
#include <hip/hip_runtime.h>
#include <hip/hip_bf16.h>
#include <math.h>

// Problem constants (fixed shapes from setup_inputs)
#define NB 8
#define CI 256
#define CD 128
#define HH 128
#define WW 128
#define HW (HH*WW)          // 16384
#define AANG 180
#define RRHO 180
#define PADD 182            // 180 + 2 (zero pad for 3x3 convs)
#define M2 (AANG*RRHO)      // 32400 output pixels per image for conv2/3

typedef __attribute__((ext_vector_type(8))) short short8;
typedef __attribute__((ext_vector_type(4))) float floatx4;

static __device__ __forceinline__ void async_cp16(const void* g, void* l) {
  __builtin_amdgcn_global_load_lds((const __attribute__((address_space(1))) unsigned int*)g,
                                   (__attribute__((address_space(3))) unsigned int*)l,
                                   16, 0, 0);
}

static __device__ __forceinline__ unsigned short f2bf(float f) {
  unsigned int u = __builtin_bit_cast(unsigned int, f);
  unsigned int r = (u + 0x7fffu + ((u >> 16) & 1u)) >> 16;
  return (unsigned short)r;
}

// ---------------------------------------------------------------------------
// prep: weight bf16 repack (k-contiguous per co) + BN scale/shift folding
// wK2/wK3 layout: [co][k], k = (dy*3+dx)*128 + ci
// ---------------------------------------------------------------------------
__global__ void prep_kernel(const float* __restrict__ w1, const float* __restrict__ w2,
                            const float* __restrict__ w3,
                            const float* b1, const float* g1, const float* be1,
                            const float* m1, const float* v1,
                            const float* b2, const float* g2, const float* be2,
                            const float* m2, const float* v2,
                            const float* b3, const float* g3, const float* be3,
                            const float* m3, const float* v3,
                            unsigned short* __restrict__ wK1, unsigned short* __restrict__ wK2,
                            unsigned short* __restrict__ wK3,
                            float* __restrict__ sc, float* __restrict__ sh) {
  int idx = blockIdx.x * 256 + threadIdx.x;
  if (idx < 32768) {
    wK1[idx] = f2bf(w1[idx]);                      // w1 is already [co][ci]
  } else if (idx < 32768 + 147456) {
    int i = idx - 32768;
    int co = i / 1152, k = i % 1152;
    int dydx = k >> 7, ci = k & 127;
    wK2[(size_t)co*1152 + k] = f2bf(w2[(size_t)(co*128 + ci)*9 + dydx]);
  } else if (idx < 32768 + 2*147456) {
    int i = idx - 32768 - 147456;
    int co = i / 1152, k = i % 1152;
    int dydx = k >> 7, ci = k & 127;
    wK3[(size_t)co*1152 + k] = f2bf(w3[(size_t)(co*128 + ci)*9 + dydx]);
  } else if (idx < 32768 + 2*147456 + 384) {
    int j = idx - 32768 - 2*147456;
    int c = j >> 7, co = j & 127;
    const float* b  = c==0?b1 :(c==1?b2 :b3);
    const float* g  = c==0?g1 :(c==1?g2 :g3);
    const float* be = c==0?be1:(c==1?be2:be3);
    const float* m  = c==0?m1 :(c==1?m2 :m3);
    const float* v  = c==0?v1 :(c==1?v2 :v3);
    float s = g[co] * rsqrtf(v[co] + 1e-5f);
    sc[c*128 + co] = s;
    sh[c*128 + co] = (b[co] - m[co]) * s + be[co];
  }
}

// ---------------------------------------------------------------------------
// Hough binning tables. fp64 to exactly match numpy (round-half-even via rint).
// irho = int(sqrt(128^2+128^2)+1)/(180-1) = 182/179
// ---------------------------------------------------------------------------
__global__ void hist_kernel(unsigned char* __restrict__ seg, unsigned int* __restrict__ offs) {
  int a = blockIdx.x, t = threadIdx.x;
  __shared__ unsigned int h[RRHO];
  if (t < RRHO) h[t] = 0;
  __syncthreads();
  double th = (double)a * (M_PI / 180.0);
  double Cc = cos(th) / (182.0 / 179.0);
  double Ss = sin(th) / (182.0 / 179.0);
  for (int p = t; p < HW; p += 256) {
    int x = (p & 127) - 64;   // width index
    int y = (p >> 7) - 64;    // height index
    int r = (int)rint(Cc * (double)x + Ss * (double)y) + 90;
    r = r < 0 ? 0 : (r > 179 ? 179 : r);
    seg[(size_t)a*HW + p] = (unsigned char)r;
    atomicAdd(&h[r], 1u);
  }
  __syncthreads();
  if (t == 0) {
    unsigned int run = 0;
    for (int r = 0; r < RRHO; ++r) { offs[a*192 + r] = run; run += h[r]; }
    offs[a*192 + RRHO] = run;
  }
}

// Pixel lists packed as ushort (p < 16384 fits) -> 32 KB per angle.
__global__ void fill_kernel(const unsigned char* __restrict__ seg,
                            const unsigned int* __restrict__ offs,
                            unsigned short* __restrict__ lst16) {
  int a = blockIdx.x, t = threadIdx.x;
  __shared__ unsigned int pos[RRHO];
  if (t < RRHO) pos[t] = offs[a*192 + t];
  __syncthreads();
  for (int p = t; p < HW; p += 256) {
    int r = seg[(size_t)a*HW + p];
    unsigned int ix = atomicAdd(&pos[r], 1u);
    lst16[(size_t)a*HW + ix] = (unsigned short)p;
  }
}

// Zero the 1-px borders of the two padded activation buffers (ws is poisoned).
__global__ void zero_border(uint4* __restrict__ accP, uint4* __restrict__ y2P) {
  int idx = blockIdx.x * 256 + threadIdx.x;
  if (idx >= NB * PADD * PADD) return;
  int rc = idx % (PADD * PADD);
  int row = rc / PADD, col = rc % PADD;
  if (row != 0 && row != PADD-1 && col != 0 && col != PADD-1) return;
  uint4 z = {0u, 0u, 0u, 0u};
  size_t base = (size_t)idx * 16;  // 128 bf16 = 16 uint4 per cell
  #pragma unroll
  for (int i = 0; i < 16; ++i) { accP[base + i] = z; y2P[base + i] = z; }
}

// ---------------------------------------------------------------------------
// conv1: 1x1 conv as MFMA GEMM. A = x (fp32, transposed+converted in staging),
// B = wK1 bf16 (global_load_lds). Output f[n][pixel][co] bf16 channels-last.
// ---------------------------------------------------------------------------
__global__ __launch_bounds__(256) void conv1_kernel(
    const float* __restrict__ x, const unsigned short* __restrict__ wK,
    const float* __restrict__ sc, const float* __restrict__ sh,
    unsigned short* __restrict__ f) {
  __shared__ short Al[4*128*8];
  __shared__ short Bl[4*128*8];
  int t = threadIdx.x;
  int m0 = blockIdx.x * 128;
  int n = blockIdx.y;
  int lane = t & 63, wv = t >> 6, wm = wv & 1, wn = wv >> 1;
  int mloc = t & 127, octb = t >> 7;
  floatx4 acc[4][4];
  #pragma unroll
  for (int i = 0; i < 4; ++i)
    #pragma unroll
    for (int j = 0; j < 4; ++j) acc[i][j] = (floatx4){0.f, 0.f, 0.f, 0.f};
  const float* xn = x + (size_t)n * CI * HW;
  for (int kc = 0; kc < 8; ++kc) {
    if (kc) __syncthreads();
    // A: load 8 k-strided fp32 per pass, convert, transpose into [oct][m][8]
    #pragma unroll
    for (int j = 0; j < 2; ++j) {
      int oct = octb + 2*j;
      const float* src = xn + (size_t)(kc*32 + oct*8) * HW + m0 + mloc;
      float v[8];
      #pragma unroll
      for (int e = 0; e < 8; ++e) v[e] = src[(size_t)e * HW];
      short8 pk;
      #pragma unroll
      for (int e = 0; e < 8; ++e) pk[e] = (short)f2bf(v[e]);
      *reinterpret_cast<short8*>(&Al[(size_t)(t + 256*j) * 8]) = pk;
    }
    // B: async 16B direct-to-LDS
    #pragma unroll
    for (int j = 0; j < 2; ++j) {
      int oct = octb + 2*j;
      async_cp16(wK + (size_t)mloc * 256 + kc*32 + oct*8,
                 &Bl[(size_t)((t & 0xFFC0) + 256*j) * 8]);
    }
    __syncthreads();
    int q = lane >> 4, l15 = lane & 15;
    short8 af[4], bfr[4];
    #pragma unroll
    for (int i = 0; i < 4; ++i)
      af[i] = *reinterpret_cast<const short8*>(&Al[((q*128) + wm*64 + i*16 + l15) * 8]);
    #pragma unroll
    for (int j = 0; j < 4; ++j)
      bfr[j] = *reinterpret_cast<const short8*>(&Bl[((q*128) + wn*64 + j*16 + l15) * 8]);
    #pragma unroll
    for (int i = 0; i < 4; ++i)
      #pragma unroll
      for (int j = 0; j < 4; ++j)
        acc[i][j] = __builtin_amdgcn_mfma_f32_16x16x32_bf16(af[i], bfr[j], acc[i][j], 0, 0, 0);
  }
  int q = lane >> 4, l15 = lane & 15;
  #pragma unroll
  for (int j = 0; j < 4; ++j) {
    int co = wn*64 + j*16 + l15;
    float s = sc[co], hb = sh[co];
    #pragma unroll
    for (int i = 0; i < 4; ++i) {
      #pragma unroll
      for (int rg = 0; rg < 4; ++rg) {
        int m = m0 + wm*64 + i*16 + q*4 + rg;
        float v = acc[i][j][rg] * s + hb;
        v = fmaxf(v, 0.f);
        f[((size_t)n * HW + m) * 128 + co] = f2bf(v);
      }
    }
  }
}

// ---------------------------------------------------------------------------
// DHT gather, round 2: per-angle pixel list staged in LDS (ushort, 32 KB),
// rho bins round-robin across the 4 waves (balance), gather unrolled x8 for
// MLP. lane = channel pair (uint = 2 bf16). Writes padded accP bf16.
// ---------------------------------------------------------------------------
__global__ __launch_bounds__(256) void dht_kernel(
    const unsigned short* __restrict__ lst16, const unsigned int* __restrict__ offs,
    const unsigned int* __restrict__ f, unsigned int* __restrict__ accP) {
  __shared__ unsigned short Ls[HW];   // 32 KB pixel list for this angle
  int b = blockIdx.x;
  int n = b & 7;               // XCD round-robin -> one image per XCD L2
  int a = b >> 3;
  int t = threadIdx.x;
  // Stage list into LDS (sequential uint4 reads, fully coalesced).
  {
    const uint4* src = (const uint4*)(lst16 + (size_t)a * HW);  // 2048 uint4
    uint4* dst = (uint4*)Ls;
    #pragma unroll
    for (int i = 0; i < 8; ++i) dst[t + 256*i] = src[t + 256*i];
  }
  __syncthreads();
  int w = t >> 6, lane = t & 63;
  const unsigned int* fn = f + (size_t)n * HW * 64;
  for (int r = w; r < RRHO; r += 4) {
    unsigned int o0 = offs[a*192 + r];
    unsigned int o1 = offs[a*192 + r + 1];
    int cnt = (int)(o1 - o0);
    float s0[4] = {0.f,0.f,0.f,0.f}, s1[4] = {0.f,0.f,0.f,0.f};
    int i = 0;
    for (; i + 8 <= cnt; i += 8) {
      unsigned int v[8];
      #pragma unroll
      for (int u = 0; u < 8; ++u) {
        int p = Ls[o0 + i + u];
        v[u] = fn[(size_t)p*64 + lane];
      }
      #pragma unroll
      for (int u = 0; u < 8; ++u) {
        s0[u & 3] += __builtin_bit_cast(float, v[u] << 16);
        s1[u & 3] += __builtin_bit_cast(float, v[u] & 0xffff0000u);
      }
    }
    for (; i < cnt; ++i) {
      int p = Ls[o0 + i];
      unsigned int v0 = fn[(size_t)p*64 + lane];
      s0[0] += __builtin_bit_cast(float, v0 << 16);
      s1[0] += __builtin_bit_cast(float, v0 & 0xffff0000u);
    }
    float r0 = (s0[0] + s0[1]) + (s0[2] + s0[3]);
    float r1 = (s1[0] + s1[1]) + (s1[2] + s1[3]);
    unsigned int packed = (unsigned int)f2bf(r0) | ((unsigned int)f2bf(r1) << 16);
    size_t o = (((size_t)n*PADD + (a+1))*PADD + (r+1))*64 + lane;
    __builtin_nontemporal_store(packed, &accP[o]);
  }
}

// ---------------------------------------------------------------------------
// 3x3 conv as implicit GEMM over padded channels-last input.
// MODE 1: conv2 -> bf16 padded channels-last out. rows = spatial, cols = co.
// MODE 2: conv3 -> fp32 NCHW d_out. Operands swapped: rows = co, cols = spatial
//         so stores are contiguous along rho.
// ---------------------------------------------------------------------------
template<int MODE>
__global__ __launch_bounds__(256) void conv3x3_kernel(
    const unsigned short* __restrict__ inP,   // [N][182][182][128] bf16
    const unsigned short* __restrict__ wK,    // [128][1152] bf16
    const float* __restrict__ sc, const float* __restrict__ sh,
    void* __restrict__ outp) {
  __shared__ short Al[4*128*8];
  __shared__ short Bl[4*128*8];
  int t = threadIdx.x;
  int m0 = blockIdx.x * 128;
  int n = blockIdx.y;
  int lane = t & 63, wv = t >> 6, wm = wv & 1, wn = wv >> 1;
  int mloc = t & 127, octb = t >> 7;
  floatx4 acc[4][4];
  #pragma unroll
  for (int i = 0; i < 4; ++i)
    #pragma unroll
    for (int j = 0; j < 4; ++j) acc[i][j] = (floatx4){0.f, 0.f, 0.f, 0.f};
  int mg = m0 + mloc; if (mg > M2 - 1) mg = M2 - 1;
  int oa = mg / 180, orr = mg % 180;
  const unsigned short* rowp = inP + (((size_t)n*PADD + oa)*PADD + orr) * 128;
  const unsigned short* wbase = wK + (size_t)mloc * 1152;
  for (int kc = 0; kc < 36; ++kc) {
    int dydx = kc >> 2, cc = kc & 3;
    int dy = dydx / 3, dx = dydx % 3;
    if (kc) __syncthreads();
    #pragma unroll
    for (int j = 0; j < 2; ++j) {
      int oct = octb + 2*j;
      async_cp16(rowp + ((dy*PADD + dx)*128) + cc*32 + oct*8,
                 &Al[(size_t)((t & 0xFFC0) + 256*j) * 8]);
      async_cp16(wbase + dydx*128 + cc*32 + oct*8,
                 &Bl[(size_t)((t & 0xFFC0) + 256*j) * 8]);
    }
    __syncthreads();
    int q = lane >> 4, l15 = lane & 15;
    short8 rf[4], cf[4];
    #pragma unroll
    for (int i = 0; i < 4; ++i) {
      int off = ((q*128) + wm*64 + i*16 + l15) * 8;
      rf[i] = *reinterpret_cast<const short8*>(MODE == 1 ? &Al[off] : &Bl[off]);
    }
    #pragma unroll
    for (int j = 0; j < 4; ++j) {
      int off = ((q*128) + wn*64 + j*16 + l15) * 8;
      cf[j] = *reinterpret_cast<const short8*>(MODE == 1 ? &Bl[off] : &Al[off]);
    }
    #pragma unroll
    for (int i = 0; i < 4; ++i)
      #pragma unroll
      for (int j = 0; j < 4; ++j)
        acc[i][j] = __builtin_amdgcn_mfma_f32_16x16x32_bf16(rf[i], cf[j], acc[i][j], 0, 0, 0);
  }
  int q = lane >> 4, l15 = lane & 15;
  if (MODE == 1) {
    unsigned short* out = (unsigned short*)outp;
    #pragma unroll
    for (int j = 0; j < 4; ++j) {
      int co = wn*64 + j*16 + l15;
      float s = sc[co], hb = sh[co];
      #pragma unroll
      for (int i = 0; i < 4; ++i) {
        #pragma unroll
        for (int rg = 0; rg < 4; ++rg) {
          int m = m0 + wm*64 + i*16 + q*4 + rg;
          if (m < M2) {
            float v = fmaxf(acc[i][j][rg] * s + hb, 0.f);
            int oa2 = m / 180, or2 = m % 180;
            out[(((size_t)n*PADD + oa2 + 1)*PADD + or2 + 1)*128 + co] = f2bf(v);
          }
        }
      }
    }
  } else {
    float* out = (float*)outp;
    #pragma unroll
    for (int i = 0; i < 4; ++i) {
      #pragma unroll
      for (int rg = 0; rg < 4; ++rg) {
        int co = wm*64 + i*16 + q*4 + rg;
        float s = sc[co], hb = sh[co];
        #pragma unroll
        for (int j = 0; j < 4; ++j) {
          int m = m0 + wn*64 + j*16 + l15;
          if (m < M2) {
            float v = fmaxf(acc[i][j][rg] * s + hb, 0.f);
            out[((size_t)n*128 + co)*M2 + m] = v;
          }
        }
      }
    }
  }
}

// ---------------------------------------------------------------------------
extern "C" void kernel_launch(void* const* d_in, const int* in_sizes, int n_in,
                              void* d_out, int out_size, void* d_ws, size_t ws_size,
                              hipStream_t stream) {
  const float* x  = (const float*)d_in[0];
  const float* w1 = (const float*)d_in[1];
  const float* b1 = (const float*)d_in[2];
  const float* g1 = (const float*)d_in[3];
  const float* be1= (const float*)d_in[4];
  const float* m1 = (const float*)d_in[5];
  const float* v1 = (const float*)d_in[6];
  const float* w2 = (const float*)d_in[7];
  const float* b2 = (const float*)d_in[8];
  const float* g2 = (const float*)d_in[9];
  const float* be2= (const float*)d_in[10];
  const float* m2 = (const float*)d_in[11];
  const float* v2 = (const float*)d_in[12];
  const float* w3 = (const float*)d_in[13];
  const float* b3 = (const float*)d_in[14];
  const float* g3 = (const float*)d_in[15];
  const float* be3= (const float*)d_in[16];
  const float* m3 = (const float*)d_in[17];
  const float* v3 = (const float*)d_in[18];

  size_t off = 0;
  char* ws = (char*)d_ws;
  auto alloc = [&](size_t sz) -> void* {
    void* p = ws + off;
    off = (off + sz + 255) & ~(size_t)255;
    return p;
  };
  unsigned short* fbuf = (unsigned short*)alloc((size_t)NB*HW*128*2);        // 33.6 MB
  unsigned short* accP = (unsigned short*)alloc((size_t)NB*PADD*PADD*128*2); // 67.8 MB
  unsigned short* y2P  = (unsigned short*)alloc((size_t)NB*PADD*PADD*128*2); // 67.8 MB
  unsigned short* wK1  = (unsigned short*)alloc(32768*2);
  unsigned short* wK2  = (unsigned short*)alloc(147456*2);
  unsigned short* wK3  = (unsigned short*)alloc(147456*2);
  float* sc = (float*)alloc(384*4);
  float* sh = (float*)alloc(384*4);
  unsigned char* seg  = (unsigned char*)alloc((size_t)AANG*HW);
  unsigned int* offs  = (unsigned int*)alloc((size_t)AANG*192*4);
  unsigned short* lst16 = (unsigned short*)alloc((size_t)AANG*HW*2);

  prep_kernel<<<1282, 256, 0, stream>>>(w1, w2, w3,
      b1, g1, be1, m1, v1, b2, g2, be2, m2, v2, b3, g3, be3, m3, v3,
      wK1, wK2, wK3, sc, sh);
  hist_kernel<<<AANG, 256, 0, stream>>>(seg, offs);
  fill_kernel<<<AANG, 256, 0, stream>>>(seg, offs, lst16);
  zero_border<<<(NB*PADD*PADD + 255)/256, 256, 0, stream>>>((uint4*)accP, (uint4*)y2P);
  conv1_kernel<<<dim3(HW/128, NB), 256, 0, stream>>>(x, wK1, sc, sh, fbuf);
  dht_kernel<<<NB*AANG, 256, 0, stream>>>(lst16, offs, (const unsigned int*)fbuf,
                                          (unsigned int*)accP);
  conv3x3_kernel<1><<<dim3((M2 + 127)/128, NB), 256, 0, stream>>>(
      accP, wK2, sc + 128, sh + 128, y2P);
  conv3x3_kernel<2><<<dim3((M2 + 127)/128, NB), 256, 0, stream>>>(
      y2P, wK3, sc + 256, sh + 256, d_out);
}

// Round 3
// 1022.775 us; speedup vs baseline: 1.5257x; 1.0825x over previous
//
#include <hip/hip_runtime.h>
#include <hip/hip_bf16.h>
#include <math.h>

// Problem constants (fixed shapes from setup_inputs)
#define NB 8
#define CI 256
#define CD 128
#define HH 128
#define WW 128
#define HW (HH*WW)          // 16384
#define AANG 180
#define RRHO 180
#define PADD 182            // 180 + 2 (zero pad for 3x3 convs)
#define M2 (AANG*RRHO)      // 32400 output pixels per image for conv2/3

typedef __attribute__((ext_vector_type(8))) short short8;
typedef __attribute__((ext_vector_type(4))) float floatx4;
typedef __attribute__((ext_vector_type(2))) float floatx2;

static __device__ __forceinline__ void async_cp16(const void* g, void* l) {
  __builtin_amdgcn_global_load_lds((const __attribute__((address_space(1))) unsigned int*)g,
                                   (__attribute__((address_space(3))) unsigned int*)l,
                                   16, 0, 0);
}

static __device__ __forceinline__ unsigned short f2bf(float f) {
  unsigned int u = __builtin_bit_cast(unsigned int, f);
  unsigned int r = (u + 0x7fffu + ((u >> 16) & 1u)) >> 16;
  return (unsigned short)r;
}

// ---------------------------------------------------------------------------
// prep: weight bf16 repack (k-contiguous per co) + BN scale/shift folding
// wK2/wK3 layout: [co][k], k = (dy*3+dx)*128 + ci
// ---------------------------------------------------------------------------
__global__ void prep_kernel(const float* __restrict__ w1, const float* __restrict__ w2,
                            const float* __restrict__ w3,
                            const float* b1, const float* g1, const float* be1,
                            const float* m1, const float* v1,
                            const float* b2, const float* g2, const float* be2,
                            const float* m2, const float* v2,
                            const float* b3, const float* g3, const float* be3,
                            const float* m3, const float* v3,
                            unsigned short* __restrict__ wK1, unsigned short* __restrict__ wK2,
                            unsigned short* __restrict__ wK3,
                            float* __restrict__ sc, float* __restrict__ sh) {
  int idx = blockIdx.x * 256 + threadIdx.x;
  if (idx < 32768) {
    wK1[idx] = f2bf(w1[idx]);                      // w1 is already [co][ci]
  } else if (idx < 32768 + 147456) {
    int i = idx - 32768;
    int co = i / 1152, k = i % 1152;
    int dydx = k >> 7, ci = k & 127;
    wK2[(size_t)co*1152 + k] = f2bf(w2[(size_t)(co*128 + ci)*9 + dydx]);
  } else if (idx < 32768 + 2*147456) {
    int i = idx - 32768 - 147456;
    int co = i / 1152, k = i % 1152;
    int dydx = k >> 7, ci = k & 127;
    wK3[(size_t)co*1152 + k] = f2bf(w3[(size_t)(co*128 + ci)*9 + dydx]);
  } else if (idx < 32768 + 2*147456 + 384) {
    int j = idx - 32768 - 2*147456;
    int c = j >> 7, co = j & 127;
    const float* b  = c==0?b1 :(c==1?b2 :b3);
    const float* g  = c==0?g1 :(c==1?g2 :g3);
    const float* be = c==0?be1:(c==1?be2:be3);
    const float* m  = c==0?m1 :(c==1?m2 :m3);
    const float* v  = c==0?v1 :(c==1?v2 :v3);
    float s = g[co] * rsqrtf(v[co] + 1e-5f);
    sc[c*128 + co] = s;
    sh[c*128 + co] = (b[co] - m[co]) * s + be[co];
  }
}

// ---------------------------------------------------------------------------
// Hough binning tables. fp64 to exactly match numpy (round-half-even via rint).
// irho = int(sqrt(128^2+128^2)+1)/(180-1) = 182/179
// ---------------------------------------------------------------------------
__global__ void hist_kernel(unsigned char* __restrict__ seg, unsigned int* __restrict__ offs) {
  int a = blockIdx.x, t = threadIdx.x;
  __shared__ unsigned int h[RRHO];
  if (t < RRHO) h[t] = 0;
  __syncthreads();
  double th = (double)a * (M_PI / 180.0);
  double Cc = cos(th) / (182.0 / 179.0);
  double Ss = sin(th) / (182.0 / 179.0);
  for (int p = t; p < HW; p += 256) {
    int x = (p & 127) - 64;   // width index
    int y = (p >> 7) - 64;    // height index
    int r = (int)rint(Cc * (double)x + Ss * (double)y) + 90;
    r = r < 0 ? 0 : (r > 179 ? 179 : r);
    seg[(size_t)a*HW + p] = (unsigned char)r;
    atomicAdd(&h[r], 1u);
  }
  __syncthreads();
  if (t == 0) {
    unsigned int run = 0;
    for (int r = 0; r < RRHO; ++r) { offs[a*192 + r] = run; run += h[r]; }
    offs[a*192 + RRHO] = run;
  }
}

// Pixel lists packed as ushort (p < 16384 fits) -> 32 KB per angle.
__global__ void fill_kernel(const unsigned char* __restrict__ seg,
                            const unsigned int* __restrict__ offs,
                            unsigned short* __restrict__ lst16) {
  int a = blockIdx.x, t = threadIdx.x;
  __shared__ unsigned int pos[RRHO];
  if (t < RRHO) pos[t] = offs[a*192 + t];
  __syncthreads();
  for (int p = t; p < HW; p += 256) {
    int r = seg[(size_t)a*HW + p];
    unsigned int ix = atomicAdd(&pos[r], 1u);
    lst16[(size_t)a*HW + ix] = (unsigned short)p;
  }
}

// Zero the 1-px borders of the two padded activation buffers (ws is poisoned).
__global__ void zero_border(uint4* __restrict__ accP, uint4* __restrict__ y2P) {
  int idx = blockIdx.x * 256 + threadIdx.x;
  if (idx >= NB * PADD * PADD) return;
  int rc = idx % (PADD * PADD);
  int row = rc / PADD, col = rc % PADD;
  if (row != 0 && row != PADD-1 && col != 0 && col != PADD-1) return;
  uint4 z = {0u, 0u, 0u, 0u};
  size_t base = (size_t)idx * 16;  // 128 bf16 = 16 uint4 per cell
  #pragma unroll
  for (int i = 0; i < 16; ++i) { accP[base + i] = z; y2P[base + i] = z; }
}

// ---------------------------------------------------------------------------
// conv1: 1x1 conv as MFMA GEMM. A = x (fp32, transposed+converted in staging),
// B = wK1 bf16 (global_load_lds). Output f[n][pixel][co] bf16 channels-last.
// ---------------------------------------------------------------------------
__global__ __launch_bounds__(256) void conv1_kernel(
    const float* __restrict__ x, const unsigned short* __restrict__ wK,
    const float* __restrict__ sc, const float* __restrict__ sh,
    unsigned short* __restrict__ f) {
  __shared__ short Al[4*128*8];
  __shared__ short Bl[4*128*8];
  int t = threadIdx.x;
  int m0 = blockIdx.x * 128;
  int n = blockIdx.y;
  int lane = t & 63, wv = t >> 6, wm = wv & 1, wn = wv >> 1;
  int mloc = t & 127, octb = t >> 7;
  floatx4 acc[4][4];
  #pragma unroll
  for (int i = 0; i < 4; ++i)
    #pragma unroll
    for (int j = 0; j < 4; ++j) acc[i][j] = (floatx4){0.f, 0.f, 0.f, 0.f};
  const float* xn = x + (size_t)n * CI * HW;
  for (int kc = 0; kc < 8; ++kc) {
    if (kc) __syncthreads();
    // A: load 8 k-strided fp32 per pass, convert, transpose into [oct][m][8]
    #pragma unroll
    for (int j = 0; j < 2; ++j) {
      int oct = octb + 2*j;
      const float* src = xn + (size_t)(kc*32 + oct*8) * HW + m0 + mloc;
      float v[8];
      #pragma unroll
      for (int e = 0; e < 8; ++e) v[e] = src[(size_t)e * HW];
      short8 pk;
      #pragma unroll
      for (int e = 0; e < 8; ++e) pk[e] = (short)f2bf(v[e]);
      *reinterpret_cast<short8*>(&Al[(size_t)(t + 256*j) * 8]) = pk;
    }
    // B: async 16B direct-to-LDS
    #pragma unroll
    for (int j = 0; j < 2; ++j) {
      int oct = octb + 2*j;
      async_cp16(wK + (size_t)mloc * 256 + kc*32 + oct*8,
                 &Bl[(size_t)((t & 0xFFC0) + 256*j) * 8]);
    }
    __syncthreads();
    int q = lane >> 4, l15 = lane & 15;
    short8 af[4], bfr[4];
    #pragma unroll
    for (int i = 0; i < 4; ++i)
      af[i] = *reinterpret_cast<const short8*>(&Al[((q*128) + wm*64 + i*16 + l15) * 8]);
    #pragma unroll
    for (int j = 0; j < 4; ++j)
      bfr[j] = *reinterpret_cast<const short8*>(&Bl[((q*128) + wn*64 + j*16 + l15) * 8]);
    #pragma unroll
    for (int i = 0; i < 4; ++i)
      #pragma unroll
      for (int j = 0; j < 4; ++j)
        acc[i][j] = __builtin_amdgcn_mfma_f32_16x16x32_bf16(af[i], bfr[j], acc[i][j], 0, 0, 0);
  }
  int q = lane >> 4, l15 = lane & 15;
  #pragma unroll
  for (int j = 0; j < 4; ++j) {
    int co = wn*64 + j*16 + l15;
    float s = sc[co], hb = sh[co];
    #pragma unroll
    for (int i = 0; i < 4; ++i) {
      #pragma unroll
      for (int rg = 0; rg < 4; ++rg) {
        int m = m0 + wm*64 + i*16 + q*4 + rg;
        float v = acc[i][j][rg] * s + hb;
        v = fmaxf(v, 0.f);
        f[((size_t)n * HW + m) * 128 + co] = f2bf(v);
      }
    }
  }
}

// ---------------------------------------------------------------------------
// DHT gather v3: block = (n, angle, channel-half). 8 lanes per pixel row-half,
// dwordx4 gathers (one wave-load = 8 pixels), float2 accumulators
// (v_pk_add_f32), 3-level shfl_xor butterfly per rho bin. Channel halving
// makes the working set 2.1 MB -> XCD-L2 resident; grid order keeps each
// image's half on one XCD for its 180 angle blocks.
// ---------------------------------------------------------------------------
__global__ __launch_bounds__(256) void dht_kernel(
    const unsigned short* __restrict__ lst16, const unsigned int* __restrict__ offs,
    const unsigned int* __restrict__ f, unsigned int* __restrict__ accP) {
  __shared__ unsigned short Ls[HW];     // 32 KB pixel list for this angle
  __shared__ unsigned int Os[RRHO + 1];
  int b = blockIdx.x;
  int n = b & 7;               // XCD round-robin -> one image per XCD L2
  int rest = b >> 3;           // h*180 + a  (h phases sequential per XCD)
  int a = rest % AANG;
  int h = rest / AANG;         // channel half: 0 or 1
  int t = threadIdx.x;
  // Stage list + offsets into LDS (sequential uint4 reads, fully coalesced).
  {
    const uint4* src = (const uint4*)(lst16 + (size_t)a * HW);  // 2048 uint4
    uint4* dst = (uint4*)Ls;
    #pragma unroll
    for (int i = 0; i < 8; ++i) dst[t + 256*i] = src[t + 256*i];
    if (t < RRHO + 1) Os[t] = offs[a*192 + t];
  }
  __syncthreads();
  int w = t >> 6, lane = t & 63;
  int sub = lane >> 3;         // which of 8 pixels in the load group
  int co  = lane & 7;          // channel octet within the half
  // Lane's 16B base: f uint index = pixel*64 + h*32 + co*4
  const unsigned int* fn = f + (size_t)n * HW * 64 + h*32 + co*4;
  for (int r = w; r < RRHO; r += 4) {
    int o0 = (int)Os[r];
    int cnt = (int)Os[r+1] - o0;
    floatx2 acc[4];
    #pragma unroll
    for (int j = 0; j < 4; ++j) acc[j] = (floatx2){0.f, 0.f};
    int i = 0;
    for (; i + 16 <= cnt; i += 16) {
      int p0 = Ls[o0 + i + sub];
      int p1 = Ls[o0 + i + 8 + sub];
      uint4 v0 = *(const uint4*)(fn + (size_t)p0 * 64);
      uint4 v1 = *(const uint4*)(fn + (size_t)p1 * 64);
      const unsigned int u0[4] = {v0.x, v0.y, v0.z, v0.w};
      const unsigned int u1[4] = {v1.x, v1.y, v1.z, v1.w};
      #pragma unroll
      for (int j = 0; j < 4; ++j) {
        acc[j] += (floatx2){__builtin_bit_cast(float, u0[j] << 16),
                            __builtin_bit_cast(float, u0[j] & 0xffff0000u)};
        acc[j] += (floatx2){__builtin_bit_cast(float, u1[j] << 16),
                            __builtin_bit_cast(float, u1[j] & 0xffff0000u)};
      }
    }
    for (; i + 8 <= cnt; i += 8) {
      int p0 = Ls[o0 + i + sub];
      uint4 v0 = *(const uint4*)(fn + (size_t)p0 * 64);
      const unsigned int u0[4] = {v0.x, v0.y, v0.z, v0.w};
      #pragma unroll
      for (int j = 0; j < 4; ++j)
        acc[j] += (floatx2){__builtin_bit_cast(float, u0[j] << 16),
                            __builtin_bit_cast(float, u0[j] & 0xffff0000u)};
    }
    if (i < cnt) {
      int idx = i + sub;
      int cl = idx < cnt ? idx : (cnt - 1);
      int p0 = Ls[o0 + cl];
      uint4 v0 = *(const uint4*)(fn + (size_t)p0 * 64);
      unsigned int u0[4] = {v0.x, v0.y, v0.z, v0.w};
      if (idx >= cnt) { u0[0] = 0; u0[1] = 0; u0[2] = 0; u0[3] = 0; }
      #pragma unroll
      for (int j = 0; j < 4; ++j)
        acc[j] += (floatx2){__builtin_bit_cast(float, u0[j] << 16),
                            __builtin_bit_cast(float, u0[j] & 0xffff0000u)};
    }
    // Butterfly reduce across the 8 pixel-subgroups (lane bits 3,4,5).
    #pragma unroll
    for (int m = 8; m <= 32; m <<= 1) {
      #pragma unroll
      for (int j = 0; j < 4; ++j) {
        acc[j].x += __shfl_xor(acc[j].x, m, 64);
        acc[j].y += __shfl_xor(acc[j].y, m, 64);
      }
    }
    if (sub == 0) {
      uint4 out;
      out.x = (unsigned int)f2bf(acc[0].x) | ((unsigned int)f2bf(acc[0].y) << 16);
      out.y = (unsigned int)f2bf(acc[1].x) | ((unsigned int)f2bf(acc[1].y) << 16);
      out.z = (unsigned int)f2bf(acc[2].x) | ((unsigned int)f2bf(acc[2].y) << 16);
      out.w = (unsigned int)f2bf(acc[3].x) | ((unsigned int)f2bf(acc[3].y) << 16);
      size_t o = (((size_t)n*PADD + (a+1))*PADD + (r+1))*64 + h*32 + co*4;
      *(uint4*)(accP + o) = out;
    }
  }
}

// ---------------------------------------------------------------------------
// 3x3 conv as implicit GEMM over padded channels-last input.
// MODE 1: conv2 -> bf16 padded channels-last out. rows = spatial, cols = co.
// MODE 2: conv3 -> fp32 NCHW d_out. Operands swapped: rows = co, cols = spatial
//         so stores are contiguous along rho.
// ---------------------------------------------------------------------------
template<int MODE>
__global__ __launch_bounds__(256) void conv3x3_kernel(
    const unsigned short* __restrict__ inP,   // [N][182][182][128] bf16
    const unsigned short* __restrict__ wK,    // [128][1152] bf16
    const float* __restrict__ sc, const float* __restrict__ sh,
    void* __restrict__ outp) {
  __shared__ short Al[4*128*8];
  __shared__ short Bl[4*128*8];
  int t = threadIdx.x;
  int m0 = blockIdx.x * 128;
  int n = blockIdx.y;
  int lane = t & 63, wv = t >> 6, wm = wv & 1, wn = wv >> 1;
  int mloc = t & 127, octb = t >> 7;
  floatx4 acc[4][4];
  #pragma unroll
  for (int i = 0; i < 4; ++i)
    #pragma unroll
    for (int j = 0; j < 4; ++j) acc[i][j] = (floatx4){0.f, 0.f, 0.f, 0.f};
  int mg = m0 + mloc; if (mg > M2 - 1) mg = M2 - 1;
  int oa = mg / 180, orr = mg % 180;
  const unsigned short* rowp = inP + (((size_t)n*PADD + oa)*PADD + orr) * 128;
  const unsigned short* wbase = wK + (size_t)mloc * 1152;
  for (int kc = 0; kc < 36; ++kc) {
    int dydx = kc >> 2, cc = kc & 3;
    int dy = dydx / 3, dx = dydx % 3;
    if (kc) __syncthreads();
    #pragma unroll
    for (int j = 0; j < 2; ++j) {
      int oct = octb + 2*j;
      async_cp16(rowp + ((dy*PADD + dx)*128) + cc*32 + oct*8,
                 &Al[(size_t)((t & 0xFFC0) + 256*j) * 8]);
      async_cp16(wbase + dydx*128 + cc*32 + oct*8,
                 &Bl[(size_t)((t & 0xFFC0) + 256*j) * 8]);
    }
    __syncthreads();
    int q = lane >> 4, l15 = lane & 15;
    short8 rf[4], cf[4];
    #pragma unroll
    for (int i = 0; i < 4; ++i) {
      int off = ((q*128) + wm*64 + i*16 + l15) * 8;
      rf[i] = *reinterpret_cast<const short8*>(MODE == 1 ? &Al[off] : &Bl[off]);
    }
    #pragma unroll
    for (int j = 0; j < 4; ++j) {
      int off = ((q*128) + wn*64 + j*16 + l15) * 8;
      cf[j] = *reinterpret_cast<const short8*>(MODE == 1 ? &Bl[off] : &Al[off]);
    }
    #pragma unroll
    for (int i = 0; i < 4; ++i)
      #pragma unroll
      for (int j = 0; j < 4; ++j)
        acc[i][j] = __builtin_amdgcn_mfma_f32_16x16x32_bf16(rf[i], cf[j], acc[i][j], 0, 0, 0);
  }
  int q = lane >> 4, l15 = lane & 15;
  if (MODE == 1) {
    unsigned short* out = (unsigned short*)outp;
    #pragma unroll
    for (int j = 0; j < 4; ++j) {
      int co = wn*64 + j*16 + l15;
      float s = sc[co], hb = sh[co];
      #pragma unroll
      for (int i = 0; i < 4; ++i) {
        #pragma unroll
        for (int rg = 0; rg < 4; ++rg) {
          int m = m0 + wm*64 + i*16 + q*4 + rg;
          if (m < M2) {
            float v = fmaxf(acc[i][j][rg] * s + hb, 0.f);
            int oa2 = m / 180, or2 = m % 180;
            out[(((size_t)n*PADD + oa2 + 1)*PADD + or2 + 1)*128 + co] = f2bf(v);
          }
        }
      }
    }
  } else {
    float* out = (float*)outp;
    #pragma unroll
    for (int i = 0; i < 4; ++i) {
      #pragma unroll
      for (int rg = 0; rg < 4; ++rg) {
        int co = wm*64 + i*16 + q*4 + rg;
        float s = sc[co], hb = sh[co];
        #pragma unroll
        for (int j = 0; j < 4; ++j) {
          int m = m0 + wn*64 + j*16 + l15;
          if (m < M2) {
            float v = fmaxf(acc[i][j][rg] * s + hb, 0.f);
            out[((size_t)n*128 + co)*M2 + m] = v;
          }
        }
      }
    }
  }
}

// ---------------------------------------------------------------------------
extern "C" void kernel_launch(void* const* d_in, const int* in_sizes, int n_in,
                              void* d_out, int out_size, void* d_ws, size_t ws_size,
                              hipStream_t stream) {
  const float* x  = (const float*)d_in[0];
  const float* w1 = (const float*)d_in[1];
  const float* b1 = (const float*)d_in[2];
  const float* g1 = (const float*)d_in[3];
  const float* be1= (const float*)d_in[4];
  const float* m1 = (const float*)d_in[5];
  const float* v1 = (const float*)d_in[6];
  const float* w2 = (const float*)d_in[7];
  const float* b2 = (const float*)d_in[8];
  const float* g2 = (const float*)d_in[9];
  const float* be2= (const float*)d_in[10];
  const float* m2 = (const float*)d_in[11];
  const float* v2 = (const float*)d_in[12];
  const float* w3 = (const float*)d_in[13];
  const float* b3 = (const float*)d_in[14];
  const float* g3 = (const float*)d_in[15];
  const float* be3= (const float*)d_in[16];
  const float* m3 = (const float*)d_in[17];
  const float* v3 = (const float*)d_in[18];

  size_t off = 0;
  char* ws = (char*)d_ws;
  auto alloc = [&](size_t sz) -> void* {
    void* p = ws + off;
    off = (off + sz + 255) & ~(size_t)255;
    return p;
  };
  unsigned short* fbuf = (unsigned short*)alloc((size_t)NB*HW*128*2);        // 33.6 MB
  unsigned short* accP = (unsigned short*)alloc((size_t)NB*PADD*PADD*128*2); // 67.8 MB
  unsigned short* y2P  = (unsigned short*)alloc((size_t)NB*PADD*PADD*128*2); // 67.8 MB
  unsigned short* wK1  = (unsigned short*)alloc(32768*2);
  unsigned short* wK2  = (unsigned short*)alloc(147456*2);
  unsigned short* wK3  = (unsigned short*)alloc(147456*2);
  float* sc = (float*)alloc(384*4);
  float* sh = (float*)alloc(384*4);
  unsigned char* seg  = (unsigned char*)alloc((size_t)AANG*HW);
  unsigned int* offs  = (unsigned int*)alloc((size_t)AANG*192*4);
  unsigned short* lst16 = (unsigned short*)alloc((size_t)AANG*HW*2);

  prep_kernel<<<1282, 256, 0, stream>>>(w1, w2, w3,
      b1, g1, be1, m1, v1, b2, g2, be2, m2, v2, b3, g3, be3, m3, v3,
      wK1, wK2, wK3, sc, sh);
  hist_kernel<<<AANG, 256, 0, stream>>>(seg, offs);
  fill_kernel<<<AANG, 256, 0, stream>>>(seg, offs, lst16);
  zero_border<<<(NB*PADD*PADD + 255)/256, 256, 0, stream>>>((uint4*)accP, (uint4*)y2P);
  conv1_kernel<<<dim3(HW/128, NB), 256, 0, stream>>>(x, wK1, sc, sh, fbuf);
  dht_kernel<<<NB*AANG*2, 256, 0, stream>>>(lst16, offs, (const unsigned int*)fbuf,
                                            (unsigned int*)accP);
  conv3x3_kernel<1><<<dim3((M2 + 127)/128, NB), 256, 0, stream>>>(
      accP, wK2, sc + 128, sh + 128, y2P);
  conv3x3_kernel<2><<<dim3((M2 + 127)/128, NB), 256, 0, stream>>>(
      y2P, wK3, sc + 256, sh + 256, d_out);
}

// Round 4
// 979.749 us; speedup vs baseline: 1.5927x; 1.0439x over previous
//
#include <hip/hip_runtime.h>
#include <hip/hip_bf16.h>
#include <math.h>

// Problem constants (fixed shapes from setup_inputs)
#define NB 8
#define CI 256
#define CD 128
#define HH 128
#define WW 128
#define HW (HH*WW)          // 16384
#define AANG 180
#define RRHO 180
#define PADD 182            // 180 + 2 (zero pad for 3x3 convs)
#define M2 (AANG*RRHO)      // 32400 output pixels per image for conv2/3

typedef __attribute__((ext_vector_type(8))) short short8;
typedef __attribute__((ext_vector_type(4))) float floatx4;
typedef __attribute__((ext_vector_type(2))) float floatx2;

static __device__ __forceinline__ void async_cp16(const void* g, void* l) {
  __builtin_amdgcn_global_load_lds((const __attribute__((address_space(1))) unsigned int*)g,
                                   (__attribute__((address_space(3))) unsigned int*)l,
                                   16, 0, 0);
}

static __device__ __forceinline__ unsigned short f2bf(float f) {
  unsigned int u = __builtin_bit_cast(unsigned int, f);
  unsigned int r = (u + 0x7fffu + ((u >> 16) & 1u)) >> 16;
  return (unsigned short)r;
}

// ---------------------------------------------------------------------------
// prep: weight bf16 repack (k-contiguous per co) + BN scale/shift folding
// wK2/wK3 layout: [co][k], k = (dy*3+dx)*128 + ci
// ---------------------------------------------------------------------------
__global__ void prep_kernel(const float* __restrict__ w1, const float* __restrict__ w2,
                            const float* __restrict__ w3,
                            const float* b1, const float* g1, const float* be1,
                            const float* m1, const float* v1,
                            const float* b2, const float* g2, const float* be2,
                            const float* m2, const float* v2,
                            const float* b3, const float* g3, const float* be3,
                            const float* m3, const float* v3,
                            unsigned short* __restrict__ wK1, unsigned short* __restrict__ wK2,
                            unsigned short* __restrict__ wK3,
                            float* __restrict__ sc, float* __restrict__ sh) {
  int idx = blockIdx.x * 256 + threadIdx.x;
  if (idx < 32768) {
    wK1[idx] = f2bf(w1[idx]);                      // w1 is already [co][ci]
  } else if (idx < 32768 + 147456) {
    int i = idx - 32768;
    int co = i / 1152, k = i % 1152;
    int dydx = k >> 7, ci = k & 127;
    wK2[(size_t)co*1152 + k] = f2bf(w2[(size_t)(co*128 + ci)*9 + dydx]);
  } else if (idx < 32768 + 2*147456) {
    int i = idx - 32768 - 147456;
    int co = i / 1152, k = i % 1152;
    int dydx = k >> 7, ci = k & 127;
    wK3[(size_t)co*1152 + k] = f2bf(w3[(size_t)(co*128 + ci)*9 + dydx]);
  } else if (idx < 32768 + 2*147456 + 384) {
    int j = idx - 32768 - 2*147456;
    int c = j >> 7, co = j & 127;
    const float* b  = c==0?b1 :(c==1?b2 :b3);
    const float* g  = c==0?g1 :(c==1?g2 :g3);
    const float* be = c==0?be1:(c==1?be2:be3);
    const float* m  = c==0?m1 :(c==1?m2 :m3);
    const float* v  = c==0?v1 :(c==1?v2 :v3);
    float s = g[co] * rsqrtf(v[co] + 1e-5f);
    sc[c*128 + co] = s;
    sh[c*128 + co] = (b[co] - m[co]) * s + be[co];
  }
}

// ---------------------------------------------------------------------------
// Hough binning tables. fp64 to exactly match numpy (round-half-even via rint).
// irho = int(sqrt(128^2+128^2)+1)/(180-1) = 182/179
// ---------------------------------------------------------------------------
__global__ void hist_kernel(unsigned char* __restrict__ seg, unsigned int* __restrict__ offs) {
  int a = blockIdx.x, t = threadIdx.x;
  __shared__ unsigned int h[RRHO];
  if (t < RRHO) h[t] = 0;
  __syncthreads();
  double th = (double)a * (M_PI / 180.0);
  double Cc = cos(th) / (182.0 / 179.0);
  double Ss = sin(th) / (182.0 / 179.0);
  for (int p = t; p < HW; p += 256) {
    int x = (p & 127) - 64;   // width index
    int y = (p >> 7) - 64;    // height index
    int r = (int)rint(Cc * (double)x + Ss * (double)y) + 90;
    r = r < 0 ? 0 : (r > 179 ? 179 : r);
    seg[(size_t)a*HW + p] = (unsigned char)r;
    atomicAdd(&h[r], 1u);
  }
  __syncthreads();
  if (t == 0) {
    unsigned int run = 0;
    for (int r = 0; r < RRHO; ++r) { offs[a*192 + r] = run; run += h[r]; }
    offs[a*192 + RRHO] = run;
  }
}

// Pixel lists packed as ushort (p < 16384 fits) -> 32 KB per angle.
// Each thread owns a CONTIGUOUS 64-px raster range so every bin's list is a
// concatenation of few raster-sorted runs (address locality for the gather).
__global__ void fill_kernel(const unsigned char* __restrict__ seg,
                            const unsigned int* __restrict__ offs,
                            unsigned short* __restrict__ lst16) {
  int a = blockIdx.x, t = threadIdx.x;
  __shared__ unsigned int pos[RRHO];
  if (t < RRHO) pos[t] = offs[a*192 + t];
  __syncthreads();
  int p0 = t * 64;
  for (int i = 0; i < 64; ++i) {
    int p = p0 + i;
    int r = seg[(size_t)a*HW + p];
    unsigned int ix = atomicAdd(&pos[r], 1u);
    lst16[(size_t)a*HW + ix] = (unsigned short)p;
  }
}

// Zero the 1-px borders of the two padded activation buffers (ws is poisoned),
// plus the 8 DHT work-queue counters.
__global__ void zero_border(uint4* __restrict__ accP, uint4* __restrict__ y2P,
                            unsigned int* __restrict__ qcnt) {
  int idx = blockIdx.x * 256 + threadIdx.x;
  if (idx < 8) qcnt[idx] = 0;
  if (idx >= NB * PADD * PADD) return;
  int rc = idx % (PADD * PADD);
  int row = rc / PADD, col = rc % PADD;
  if (row != 0 && row != PADD-1 && col != 0 && col != PADD-1) return;
  uint4 z = {0u, 0u, 0u, 0u};
  size_t base = (size_t)idx * 16;  // 128 bf16 = 16 uint4 per cell
  #pragma unroll
  for (int i = 0; i < 16; ++i) { accP[base + i] = z; y2P[base + i] = z; }
}

// ---------------------------------------------------------------------------
// conv1: 1x1 conv as MFMA GEMM. A = x (fp32, transposed+converted in staging),
// B = wK1 bf16 (global_load_lds). Output f[n][pixel][co] bf16 channels-last.
// ---------------------------------------------------------------------------
__global__ __launch_bounds__(256) void conv1_kernel(
    const float* __restrict__ x, const unsigned short* __restrict__ wK,
    const float* __restrict__ sc, const float* __restrict__ sh,
    unsigned short* __restrict__ f) {
  __shared__ short Al[4*128*8];
  __shared__ short Bl[4*128*8];
  int t = threadIdx.x;
  int m0 = blockIdx.x * 128;
  int n = blockIdx.y;
  int lane = t & 63, wv = t >> 6, wm = wv & 1, wn = wv >> 1;
  int mloc = t & 127, octb = t >> 7;
  floatx4 acc[4][4];
  #pragma unroll
  for (int i = 0; i < 4; ++i)
    #pragma unroll
    for (int j = 0; j < 4; ++j) acc[i][j] = (floatx4){0.f, 0.f, 0.f, 0.f};
  const float* xn = x + (size_t)n * CI * HW;
  for (int kc = 0; kc < 8; ++kc) {
    if (kc) __syncthreads();
    // A: load 8 k-strided fp32 per pass, convert, transpose into [oct][m][8]
    #pragma unroll
    for (int j = 0; j < 2; ++j) {
      int oct = octb + 2*j;
      const float* src = xn + (size_t)(kc*32 + oct*8) * HW + m0 + mloc;
      float v[8];
      #pragma unroll
      for (int e = 0; e < 8; ++e) v[e] = src[(size_t)e * HW];
      short8 pk;
      #pragma unroll
      for (int e = 0; e < 8; ++e) pk[e] = (short)f2bf(v[e]);
      *reinterpret_cast<short8*>(&Al[(size_t)(t + 256*j) * 8]) = pk;
    }
    // B: async 16B direct-to-LDS
    #pragma unroll
    for (int j = 0; j < 2; ++j) {
      int oct = octb + 2*j;
      async_cp16(wK + (size_t)mloc * 256 + kc*32 + oct*8,
                 &Bl[(size_t)((t & 0xFFC0) + 256*j) * 8]);
    }
    __syncthreads();
    int q = lane >> 4, l15 = lane & 15;
    short8 af[4], bfr[4];
    #pragma unroll
    for (int i = 0; i < 4; ++i)
      af[i] = *reinterpret_cast<const short8*>(&Al[((q*128) + wm*64 + i*16 + l15) * 8]);
    #pragma unroll
    for (int j = 0; j < 4; ++j)
      bfr[j] = *reinterpret_cast<const short8*>(&Bl[((q*128) + wn*64 + j*16 + l15) * 8]);
    #pragma unroll
    for (int i = 0; i < 4; ++i)
      #pragma unroll
      for (int j = 0; j < 4; ++j)
        acc[i][j] = __builtin_amdgcn_mfma_f32_16x16x32_bf16(af[i], bfr[j], acc[i][j], 0, 0, 0);
  }
  int q = lane >> 4, l15 = lane & 15;
  #pragma unroll
  for (int j = 0; j < 4; ++j) {
    int co = wn*64 + j*16 + l15;
    float s = sc[co], hb = sh[co];
    #pragma unroll
    for (int i = 0; i < 4; ++i) {
      #pragma unroll
      for (int rg = 0; rg < 4; ++rg) {
        int m = m0 + wm*64 + i*16 + q*4 + rg;
        float v = acc[i][j][rg] * s + hb;
        v = fmaxf(v, 0.f);
        f[((size_t)n * HW + m) * 128 + co] = f2bf(v);
      }
    }
  }
}

// ---------------------------------------------------------------------------
// DHT gather v4: work claimed from per-XCD queues via HW_REG_XCC_ID so each
// XCD provably processes one image-half (2.1 MB -> its own L2) regardless of
// the HW workgroup->XCD mapping. 8 lanes per pixel half-row, dwordx4 gathers,
// 32 px/iter (4 loads in flight), float2 accumulators, 3-level shfl butterfly.
// ---------------------------------------------------------------------------
__global__ __launch_bounds__(256, 4) void dht_kernel(
    const unsigned short* __restrict__ lst16, const unsigned int* __restrict__ offs,
    const unsigned int* __restrict__ f, unsigned int* __restrict__ accP,
    unsigned int* __restrict__ qcnt) {
  __shared__ unsigned short Ls[HW];     // 32 KB pixel list for this angle
  __shared__ unsigned int Os[RRHO + 1];
  __shared__ int sWork;
  int t = threadIdx.x;
  if (t == 0) {
    unsigned int xcd;
    asm volatile("s_getreg_b32 %0, hwreg(HW_REG_XCC_ID, 0, 32)" : "=s"(xcd));
    xcd &= 7u;
    int work = 0;
    for (int k = 0; k < 8; ++k) {
      unsigned int q = (xcd + (unsigned int)k) & 7u;
      unsigned int tk = atomicAdd(&qcnt[q], 1u);
      if (tk < 360u) { work = (int)(q * 360u + tk); break; }
    }
    sWork = work;
  }
  __syncthreads();
  int work = sWork;
  int n = work / 360;          // image == (ideally) this XCD
  int rem = work % 360;
  int h = rem / 180;           // channel half; co-resident tickets share h
  int a = rem % 180;
  // Stage list + offsets into LDS (sequential uint4 reads, fully coalesced).
  {
    const uint4* src = (const uint4*)(lst16 + (size_t)a * HW);  // 2048 uint4
    uint4* dst = (uint4*)Ls;
    if (t < RRHO + 1) Os[t] = offs[a*192 + t];
    #pragma unroll
    for (int i = 0; i < 8; ++i) dst[t + 256*i] = src[t + 256*i];
  }
  __syncthreads();
  int w = t >> 6, lane = t & 63;
  int sub = lane >> 3;         // which of 8 pixels in the load group
  int co  = lane & 7;          // channel octet within the half
  // Lane's 16B base: f uint index = pixel*64 + h*32 + co*4
  const unsigned int* fn = f + (size_t)n * HW * 64 + h*32 + co*4;
  for (int r = w; r < RRHO; r += 4) {
    int o0 = (int)Os[r];
    int cnt = (int)Os[r+1] - o0;
    floatx2 acc[4];
    #pragma unroll
    for (int j = 0; j < 4; ++j) acc[j] = (floatx2){0.f, 0.f};
    int i = 0;
    for (; i + 32 <= cnt; i += 32) {
      int p0 = Ls[o0 + i + sub];
      int p1 = Ls[o0 + i + 8 + sub];
      int p2 = Ls[o0 + i + 16 + sub];
      int p3 = Ls[o0 + i + 24 + sub];
      uint4 v0 = *(const uint4*)(fn + (size_t)p0 * 64);
      uint4 v1 = *(const uint4*)(fn + (size_t)p1 * 64);
      uint4 v2 = *(const uint4*)(fn + (size_t)p2 * 64);
      uint4 v3 = *(const uint4*)(fn + (size_t)p3 * 64);
      const unsigned int u0[4] = {v0.x, v0.y, v0.z, v0.w};
      const unsigned int u1[4] = {v1.x, v1.y, v1.z, v1.w};
      const unsigned int u2[4] = {v2.x, v2.y, v2.z, v2.w};
      const unsigned int u3[4] = {v3.x, v3.y, v3.z, v3.w};
      #pragma unroll
      for (int j = 0; j < 4; ++j) {
        acc[j] += (floatx2){__builtin_bit_cast(float, u0[j] << 16),
                            __builtin_bit_cast(float, u0[j] & 0xffff0000u)};
        acc[j] += (floatx2){__builtin_bit_cast(float, u1[j] << 16),
                            __builtin_bit_cast(float, u1[j] & 0xffff0000u)};
        acc[j] += (floatx2){__builtin_bit_cast(float, u2[j] << 16),
                            __builtin_bit_cast(float, u2[j] & 0xffff0000u)};
        acc[j] += (floatx2){__builtin_bit_cast(float, u3[j] << 16),
                            __builtin_bit_cast(float, u3[j] & 0xffff0000u)};
      }
    }
    for (; i + 8 <= cnt; i += 8) {
      int p0 = Ls[o0 + i + sub];
      uint4 v0 = *(const uint4*)(fn + (size_t)p0 * 64);
      const unsigned int u0[4] = {v0.x, v0.y, v0.z, v0.w};
      #pragma unroll
      for (int j = 0; j < 4; ++j)
        acc[j] += (floatx2){__builtin_bit_cast(float, u0[j] << 16),
                            __builtin_bit_cast(float, u0[j] & 0xffff0000u)};
    }
    if (i < cnt) {
      int idx = i + sub;
      int cl = idx < cnt ? idx : (cnt - 1);
      int p0 = Ls[o0 + cl];
      uint4 v0 = *(const uint4*)(fn + (size_t)p0 * 64);
      unsigned int u0[4] = {v0.x, v0.y, v0.z, v0.w};
      if (idx >= cnt) { u0[0] = 0; u0[1] = 0; u0[2] = 0; u0[3] = 0; }
      #pragma unroll
      for (int j = 0; j < 4; ++j)
        acc[j] += (floatx2){__builtin_bit_cast(float, u0[j] << 16),
                            __builtin_bit_cast(float, u0[j] & 0xffff0000u)};
    }
    // Butterfly reduce across the 8 pixel-subgroups (lane bits 3,4,5).
    #pragma unroll
    for (int m = 8; m <= 32; m <<= 1) {
      #pragma unroll
      for (int j = 0; j < 4; ++j) {
        acc[j].x += __shfl_xor(acc[j].x, m, 64);
        acc[j].y += __shfl_xor(acc[j].y, m, 64);
      }
    }
    if (sub == 0) {
      uint4 out;
      out.x = (unsigned int)f2bf(acc[0].x) | ((unsigned int)f2bf(acc[0].y) << 16);
      out.y = (unsigned int)f2bf(acc[1].x) | ((unsigned int)f2bf(acc[1].y) << 16);
      out.z = (unsigned int)f2bf(acc[2].x) | ((unsigned int)f2bf(acc[2].y) << 16);
      out.w = (unsigned int)f2bf(acc[3].x) | ((unsigned int)f2bf(acc[3].y) << 16);
      size_t o = (((size_t)n*PADD + (a+1))*PADD + (r+1))*64 + h*32 + co*4;
      *(uint4*)(accP + o) = out;
    }
  }
}

// ---------------------------------------------------------------------------
// 3x3 conv as implicit GEMM over padded channels-last input.
// MODE 1: conv2 -> bf16 padded channels-last out. rows = spatial, cols = co.
// MODE 2: conv3 -> fp32 NCHW d_out. Operands swapped: rows = co, cols = spatial
//         so stores are contiguous along rho.
// ---------------------------------------------------------------------------
template<int MODE>
__global__ __launch_bounds__(256) void conv3x3_kernel(
    const unsigned short* __restrict__ inP,   // [N][182][182][128] bf16
    const unsigned short* __restrict__ wK,    // [128][1152] bf16
    const float* __restrict__ sc, const float* __restrict__ sh,
    void* __restrict__ outp) {
  __shared__ short Al[4*128*8];
  __shared__ short Bl[4*128*8];
  int t = threadIdx.x;
  int m0 = blockIdx.x * 128;
  int n = blockIdx.y;
  int lane = t & 63, wv = t >> 6, wm = wv & 1, wn = wv >> 1;
  int mloc = t & 127, octb = t >> 7;
  floatx4 acc[4][4];
  #pragma unroll
  for (int i = 0; i < 4; ++i)
    #pragma unroll
    for (int j = 0; j < 4; ++j) acc[i][j] = (floatx4){0.f, 0.f, 0.f, 0.f};
  int mg = m0 + mloc; if (mg > M2 - 1) mg = M2 - 1;
  int oa = mg / 180, orr = mg % 180;
  const unsigned short* rowp = inP + (((size_t)n*PADD + oa)*PADD + orr) * 128;
  const unsigned short* wbase = wK + (size_t)mloc * 1152;
  for (int kc = 0; kc < 36; ++kc) {
    int dydx = kc >> 2, cc = kc & 3;
    int dy = dydx / 3, dx = dydx % 3;
    if (kc) __syncthreads();
    #pragma unroll
    for (int j = 0; j < 2; ++j) {
      int oct = octb + 2*j;
      async_cp16(rowp + ((dy*PADD + dx)*128) + cc*32 + oct*8,
                 &Al[(size_t)((t & 0xFFC0) + 256*j) * 8]);
      async_cp16(wbase + dydx*128 + cc*32 + oct*8,
                 &Bl[(size_t)((t & 0xFFC0) + 256*j) * 8]);
    }
    __syncthreads();
    int q = lane >> 4, l15 = lane & 15;
    short8 rf[4], cf[4];
    #pragma unroll
    for (int i = 0; i < 4; ++i) {
      int off = ((q*128) + wm*64 + i*16 + l15) * 8;
      rf[i] = *reinterpret_cast<const short8*>(MODE == 1 ? &Al[off] : &Bl[off]);
    }
    #pragma unroll
    for (int j = 0; j < 4; ++j) {
      int off = ((q*128) + wn*64 + j*16 + l15) * 8;
      cf[j] = *reinterpret_cast<const short8*>(MODE == 1 ? &Bl[off] : &Al[off]);
    }
    #pragma unroll
    for (int i = 0; i < 4; ++i)
      #pragma unroll
      for (int j = 0; j < 4; ++j)
        acc[i][j] = __builtin_amdgcn_mfma_f32_16x16x32_bf16(rf[i], cf[j], acc[i][j], 0, 0, 0);
  }
  int q = lane >> 4, l15 = lane & 15;
  if (MODE == 1) {
    unsigned short* out = (unsigned short*)outp;
    #pragma unroll
    for (int j = 0; j < 4; ++j) {
      int co = wn*64 + j*16 + l15;
      float s = sc[co], hb = sh[co];
      #pragma unroll
      for (int i = 0; i < 4; ++i) {
        #pragma unroll
        for (int rg = 0; rg < 4; ++rg) {
          int m = m0 + wm*64 + i*16 + q*4 + rg;
          if (m < M2) {
            float v = fmaxf(acc[i][j][rg] * s + hb, 0.f);
            int oa2 = m / 180, or2 = m % 180;
            out[(((size_t)n*PADD + oa2 + 1)*PADD + or2 + 1)*128 + co] = f2bf(v);
          }
        }
      }
    }
  } else {
    float* out = (float*)outp;
    #pragma unroll
    for (int i = 0; i < 4; ++i) {
      #pragma unroll
      for (int rg = 0; rg < 4; ++rg) {
        int co = wm*64 + i*16 + q*4 + rg;
        float s = sc[co], hb = sh[co];
        #pragma unroll
        for (int j = 0; j < 4; ++j) {
          int m = m0 + wn*64 + j*16 + l15;
          if (m < M2) {
            float v = fmaxf(acc[i][j][rg] * s + hb, 0.f);
            out[((size_t)n*128 + co)*M2 + m] = v;
          }
        }
      }
    }
  }
}

// ---------------------------------------------------------------------------
extern "C" void kernel_launch(void* const* d_in, const int* in_sizes, int n_in,
                              void* d_out, int out_size, void* d_ws, size_t ws_size,
                              hipStream_t stream) {
  const float* x  = (const float*)d_in[0];
  const float* w1 = (const float*)d_in[1];
  const float* b1 = (const float*)d_in[2];
  const float* g1 = (const float*)d_in[3];
  const float* be1= (const float*)d_in[4];
  const float* m1 = (const float*)d_in[5];
  const float* v1 = (const float*)d_in[6];
  const float* w2 = (const float*)d_in[7];
  const float* b2 = (const float*)d_in[8];
  const float* g2 = (const float*)d_in[9];
  const float* be2= (const float*)d_in[10];
  const float* m2 = (const float*)d_in[11];
  const float* v2 = (const float*)d_in[12];
  const float* w3 = (const float*)d_in[13];
  const float* b3 = (const float*)d_in[14];
  const float* g3 = (const float*)d_in[15];
  const float* be3= (const float*)d_in[16];
  const float* m3 = (const float*)d_in[17];
  const float* v3 = (const float*)d_in[18];

  size_t off = 0;
  char* ws = (char*)d_ws;
  auto alloc = [&](size_t sz) -> void* {
    void* p = ws + off;
    off = (off + sz + 255) & ~(size_t)255;
    return p;
  };
  unsigned short* fbuf = (unsigned short*)alloc((size_t)NB*HW*128*2);        // 33.6 MB
  unsigned short* accP = (unsigned short*)alloc((size_t)NB*PADD*PADD*128*2); // 67.8 MB
  unsigned short* y2P  = (unsigned short*)alloc((size_t)NB*PADD*PADD*128*2); // 67.8 MB
  unsigned short* wK1  = (unsigned short*)alloc(32768*2);
  unsigned short* wK2  = (unsigned short*)alloc(147456*2);
  unsigned short* wK3  = (unsigned short*)alloc(147456*2);
  float* sc = (float*)alloc(384*4);
  float* sh = (float*)alloc(384*4);
  unsigned char* seg  = (unsigned char*)alloc((size_t)AANG*HW);
  unsigned int* offs  = (unsigned int*)alloc((size_t)AANG*192*4);
  unsigned short* lst16 = (unsigned short*)alloc((size_t)AANG*HW*2);
  unsigned int* qcnt  = (unsigned int*)alloc(8*4);

  prep_kernel<<<1282, 256, 0, stream>>>(w1, w2, w3,
      b1, g1, be1, m1, v1, b2, g2, be2, m2, v2, b3, g3, be3, m3, v3,
      wK1, wK2, wK3, sc, sh);
  hist_kernel<<<AANG, 256, 0, stream>>>(seg, offs);
  fill_kernel<<<AANG, 256, 0, stream>>>(seg, offs, lst16);
  zero_border<<<(NB*PADD*PADD + 255)/256, 256, 0, stream>>>((uint4*)accP, (uint4*)y2P, qcnt);
  conv1_kernel<<<dim3(HW/128, NB), 256, 0, stream>>>(x, wK1, sc, sh, fbuf);
  dht_kernel<<<NB*AANG*2, 256, 0, stream>>>(lst16, offs, (const unsigned int*)fbuf,
                                            (unsigned int*)accP, qcnt);
  conv3x3_kernel<1><<<dim3((M2 + 127)/128, NB), 256, 0, stream>>>(
      accP, wK2, sc + 128, sh + 128, y2P);
  conv3x3_kernel<2><<<dim3((M2 + 127)/128, NB), 256, 0, stream>>>(
      y2P, wK3, sc + 256, sh + 256, d_out);
}